// Round 5
// baseline (331.737 us; speedup 1.0000x reference)
//
#include <hip/hip_runtime.h>

// Quantum conv circuit, 16 qubits, batch 16.
// Round 5: persistent single kernel, plain launch (cooperative launch is broken in
//   this harness -> rounds 3/4 never executed). Manual device-scope atomic grid
//   barrier between phases. 512 blocks x 256 threads (2 tiles/block), provably
//   co-resident: LDS 18.8KB (8/CU fit), launch_bounds(256,2) -> 2 blocks/CU x 256 CUs.
// State: float2[16][65536] at d_ws; barrier counters at d_ws + 8MB (memset each call).
// Bit convention: wire w <-> flat-index bit p = 15-w.
// Gate index: L1d0(p)=15-p, L1d1(p)=16+(15-p), L2d0(p)=32+(15-p)/2, L2d1(p)=40+(15-p)/2,
//             L3d0(p)=48+(15-p)/4, L3d1(p)=52+(15-p)/4, L4d0(p)=56+(15-p)/8, L4d1(p)=58+(15-p)/8.

#define DEV __device__ __forceinline__
#define TB(i) (tbs + (i)*8)

#define NBLK 512u

__device__ static const unsigned char G_CP[60] = {
  15,14,13,12,11,10,9,8,7,6,5,4,3,2,1,0,
  15,14,13,12,11,10,9,8,7,6,5,4,3,2,1,0,
  15,13,11,9,7,5,3,1,
  15,13,11,9,7,5,3,1,
  15,11,7,3,
  15,11,7,3,
  15,7,
  15,7
};
__device__ static const unsigned char G_CQ[60] = {
  14,13,12,11,10,9,8,7,6,5,4,3,2,1,0,15,
  14,13,12,11,10,9,8,7,6,5,4,3,2,1,0,15,
  13,11,9,7,5,3,1,15,
  13,11,9,7,5,3,1,15,
  11,7,3,15,
  11,7,3,15,
  7,15,
  7,15
};

DEV float2 F2(float x, float y){ float2 r; r.x = x; r.y = y; return r; }
DEV float2 cmulf(float2 a, float2 b){ return F2(a.x*b.x - a.y*b.y, a.x*b.y + a.y*b.x); }
// XOR bank swizzle on float2 slot index (32 banks = 16 float2 columns); maps [0,1024)->[0,1024).
DEV int swz(int j){ return j ^ ((j>>4)&15) ^ ((j>>6)&15); }

// Device-scope grid barrier (persistent-kernel). Release fence -> device-scope
// atomic arrive -> acquire spin; all threads fence after. Counters zeroed host-side.
DEV void gbar(unsigned* cnt){
  __syncthreads();
  if (threadIdx.x == 0){
    __threadfence();   // release: write back dirty lines so other XCDs see our st writes
    __hip_atomic_fetch_add(cnt, 1u, __ATOMIC_ACQ_REL, __HIP_MEMORY_SCOPE_AGENT);
    while (__hip_atomic_load(cnt, __ATOMIC_ACQUIRE, __HIP_MEMORY_SCOPE_AGENT) < NBLK){
      __builtin_amdgcn_s_sleep(2);
    }
  }
  __syncthreads();
  __threadfence();     // acquire: invalidate stale L1/L2 before reading other blocks' writes
}

// 2x2 unitary on register slot bit B of a[8].
template<int B>
DEV void gate8(float2* a, const float* g){
  float u00r=g[0],u00i=g[1],u01r=g[2],u01i=g[3],u10r=g[4],u10i=g[5],u11r=g[6],u11i=g[7];
  #pragma unroll
  for (int m=0; m<4; m++){
    int i0 = ((m>>B)<<(B+1)) | (m & ((1<<B)-1));
    int i1 = i0 | (1<<B);
    float2 x0=a[i0], x1=a[i1];
    a[i0] = F2(u00r*x0.x - u00i*x0.y + u01r*x1.x - u01i*x1.y,
               u00r*x0.y + u00i*x0.x + u01r*x1.y + u01i*x1.x);
    a[i1] = F2(u10r*x0.x - u10i*x0.y + u11r*x1.x - u11i*x1.y,
               u10r*x0.y + u10i*x0.x + u11r*x1.y + u11i*x1.x);
  }
}

template<int CB,int TBIT>
DEV void cnot8(float2* a){
  #pragma unroll
  for (int r=0; r<8; r++){
    if ( ((r>>CB)&1)==1 && ((r>>TBIT)&1)==0 ){
      float2 tmp = a[r]; a[r] = a[r | (1<<TBIT)]; a[r | (1<<TBIT)] = tmp;
    }
  }
}

// RZZ diagonal round, couplings [C0,C0+N). Ib = global 16-bit index with reg bits = 0.
template<int C0,int N,unsigned M0,unsigned M1,unsigned M2>
DEV void diag8(float2* a, const float* tbs, unsigned Ib){
  const unsigned regmask = M0|M1|M2;
  float2 F0 = F2(1.f, 0.f);
  #pragma unroll
  for (int k=0; k<N; k++){
    const int p = G_CP[C0+k], q = G_CQ[C0+k];
    if ( !(((1u<<p)|(1u<<q)) & regmask) ){
      float c = tbs[480 + 2*(C0+k)], s = tbs[481 + 2*(C0+k)];
      unsigned x = ((Ib>>p) ^ (Ib>>q)) & 1u;
      F0 = cmulf(F0, F2(c, x ? s : -s));
    }
  }
  #pragma unroll
  for (int r=0; r<8; r++){
    unsigned Ir = Ib ^ ((r&1)?M0:0u) ^ ((r&2)?M1:0u) ^ ((r&4)?M2:0u);
    float2 ph = F0;
    #pragma unroll
    for (int k=0; k<N; k++){
      const int p = G_CP[C0+k], q = G_CQ[C0+k];
      if ( ((1u<<p)|(1u<<q)) & regmask ){
        float c = tbs[480 + 2*(C0+k)], s = tbs[481 + 2*(C0+k)];
        unsigned x = ((Ir>>p) ^ (Ir>>q)) & 1u;
        ph = cmulf(ph, F2(c, x ? s : -s));
      }
    }
    a[r] = cmulf(a[r], ph);
  }
}

// index helpers — verbatim from round-2 (correctness-verified at absmax 3.05e-5)
DEV unsigned p2I(int j, int o){ return (unsigned)((j&15) | (o<<4) | ((j>>4)<<10)); }
DEV unsigned p4I(int j, unsigned og){
  return (unsigned)( (j&15) | (((j>>4)&1)<<5) | (((j>>5)&1)<<7) | (((j>>6)&1)<<9)
                   | (((j>>7)&1)<<11) | (((j>>8)&1)<<13) | (((j>>9)&1)<<15) ) | og;
}
DEV int p4_jA(int t,int r){ return t | (r<<7); }                                   // slots g11,g13,g15
DEV int p4_jB(int t,int r){ return (t&15) | (r<<4) | ((t>>4)<<7); }                // slots g5,g7,g9
DEV int p4_jC(int t,int r){ return (t&1) | ((r&1)<<1) | (((t>>1)&1)<<2) | (((r>>1)&1)<<3)
                                  | (((t>>2)&1)<<4) | (((r>>2)&1)<<5) | ((t>>3)<<6); } // slots g1,g3,g7
DEV int p4_jD(int t,int r){ return (t&15) | ((r&1)<<4) | (((t>>4)&1)<<5) | (((r>>1)&1)<<6)
                                  | (((t>>5)&1)<<7) | (((r>>2)&1)<<8) | ((t>>6)<<9); } // slots g5,g9,g13
DEV int p4_jF(int t,int r){ return (t&63) | ((r&1)<<6) | (((r>>1)&1)<<7) | (((t>>6)&1)<<8) | ((r>>2)<<9); } // g9,g11,g15
DEV int p4_jG(int t,int r){ return (t&15) | ((r&3)<<4) | (((t>>4)&7)<<6) | ((r>>2)<<9); } // slots g5,g7,g15
DEV int p4_jJ(int t,int r){ return (t&7) | ((r&1)<<3) | (((t>>3)&1)<<4) | (((r>>1)&1)<<5)
                                  | (((t>>4)&7)<<6) | ((r>>2)<<9); }               // slots g3,g7,g15

__global__ __launch_bounds__(256, 2)
void k_fused(const float* __restrict__ xre, const float* __restrict__ xim,
             const float* __restrict__ p0, const float* __restrict__ p1,
             const float* __restrict__ p2, const float* __restrict__ p3,
             float2* __restrict__ st, unsigned* __restrict__ bar,
             float* __restrict__ out){
  const int t  = threadIdx.x;
  const int ti = t & 127;                       // thread id within tile
  const int half = t >> 7;                      // which tile of this block
  const int tile = (blockIdx.x << 1) | half;    // 0..1023
  const int batch = tile >> 6, o = tile & 63;
  const unsigned bb = (unsigned)batch<<16;
  const unsigned hi10 = bb | ((unsigned)o<<10);
  __shared__ float2 lds[2048];                  // one 1024-slot buffer per half
  __shared__ float tbs[600];
  __shared__ float red[4];
  float2* L = lds + (half<<10);
  float2 a[8];

  // ---- gate-table build (double precision), per-block ----
  if (t < 60){
    int g = t;
    int d, j, n; const float* P;
    if (g < 32)      { n=16; d=(g>>4)&1; j=g&15; P=p0; }
    else if (g < 48) { n=8;  d=(g>>3)&1; j=g&7;  P=p1; }
    else if (g < 56) { n=4;  d=(g>>2)&1; j=g&3;  P=p2; }
    else             { n=2;  d=(g>>1)&1; j=g&1;  P=p3; }
    int base = 4*j + 4*n*d;
    double th0 = P[base+0], th1 = P[base+1], th2 = P[base+2], th3 = P[base+3];
    double c0 = cos(th0*0.5), s0 = sin(th0*0.5);
    double ca = cos(th1*0.5), sa = sin(th1*0.5);
    double c2 = cos(th2*0.5), s2 = sin(th2*0.5);
    double B00r =  ca*c0, B00i = -sa*c0;
    double B01r = -sa*s0, B01i = -ca*s0;
    double B10r =  sa*s0, B10i = -ca*s0;
    double B11r =  ca*c0, B11i =  sa*c0;
    float* oo = tbs + g*8;
    oo[0]=(float)(c2*B00r + s2*B10i); oo[1]=(float)(c2*B00i - s2*B10r);
    oo[2]=(float)(c2*B01r + s2*B11i); oo[3]=(float)(c2*B01i - s2*B11r);
    oo[4]=(float)(s2*B00i + c2*B10r); oo[5]=(float)(-s2*B00r + c2*B10i);
    oo[6]=(float)(s2*B01i + c2*B11r); oo[7]=(float)(-s2*B01r + c2*B11i);
    tbs[480 + 2*g] = (float)cos(th3*0.5);
    tbs[481 + 2*g] = (float)sin(th3*0.5);
  }
  __syncthreads();

  // ======== phase 1: L1d0 on g0..g9. inner j = g0..9, outer o = g10..15 ========
  {
    unsigned base = hi10 | ((unsigned)ti<<3);
    float4 r0 = *(const float4*)(xre+base), r1 = *(const float4*)(xre+base+4);
    float4 i0 = *(const float4*)(xim+base), i1 = *(const float4*)(xim+base+4);
    a[0]=F2(r0.x,i0.x); a[1]=F2(r0.y,i0.y); a[2]=F2(r0.z,i0.z); a[3]=F2(r0.w,i0.w);
    a[4]=F2(r1.x,i1.x); a[5]=F2(r1.y,i1.y); a[6]=F2(r1.z,i1.z); a[7]=F2(r1.w,i1.w);
  }
  gate8<0>(a, TB(15)); gate8<1>(a, TB(14)); gate8<2>(a, TB(13));
  #pragma unroll
  for (int r=0;r<8;r++) L[swz(r | (ti<<3))] = a[r];
  __syncthreads();
  #pragma unroll
  for (int r=0;r<8;r++) a[r] = L[swz((ti&7) | (r<<3) | ((ti>>3)<<6))];
  __syncthreads();
  gate8<0>(a, TB(12)); gate8<1>(a, TB(11)); gate8<2>(a, TB(10));
  #pragma unroll
  for (int r=0;r<8;r++) L[swz((ti&7) | (r<<3) | ((ti>>3)<<6))] = a[r];
  __syncthreads();
  #pragma unroll
  for (int r=0;r<8;r++) a[r] = L[swz((ti&63) | (r<<6) | ((ti>>6)<<9))];
  __syncthreads();
  gate8<0>(a, TB(9)); gate8<1>(a, TB(8)); gate8<2>(a, TB(7));
  #pragma unroll
  for (int r=0;r<8;r++) L[swz((ti&63) | (r<<6) | ((ti>>6)<<9))] = a[r];
  __syncthreads();
  #pragma unroll
  for (int r=0;r<8;r++) a[r] = L[swz(ti | (r<<7))];
  gate8<2>(a, TB(6));  // g9
  #pragma unroll
  for (int r=0;r<8;r++) st[hi10 | (unsigned)(ti | (r<<7))] = a[r];

  gbar(bar+0);

  // ======== phase 2: L1d0 g10..15, D0, L1d1 on {g0..3, g10..15}. outer o = g4..9 ========
  #pragma unroll
  for (int r=0;r<8;r++) a[r] = st[bb | p2I(ti | (r<<7), o)];
  gate8<0>(a, TB(2)); gate8<1>(a, TB(1)); gate8<2>(a, TB(0));
  #pragma unroll
  for (int r=0;r<8;r++) L[swz(ti | (r<<7))] = a[r];
  __syncthreads();
  #pragma unroll
  for (int r=0;r<8;r++) a[r] = L[swz((ti&15) | (r<<4) | ((ti>>4)<<7))];
  __syncthreads();
  gate8<0>(a, TB(5)); gate8<1>(a, TB(4)); gate8<2>(a, TB(3));     // L1d0 g10,g11,g12
  diag8<0,16, (1u<<10),(1u<<11),(1u<<12)>(a, tbs, p2I((ti&15) | ((ti>>4)<<7), o));  // D0
  gate8<0>(a, TB(21)); gate8<1>(a, TB(20)); gate8<2>(a, TB(19));  // L1d1 g10,g11,g12
  #pragma unroll
  for (int r=0;r<8;r++) L[swz((ti&15) | (r<<4) | ((ti>>4)<<7))] = a[r];
  __syncthreads();
  #pragma unroll
  for (int r=0;r<8;r++) a[r] = L[swz(ti | (r<<7))];
  __syncthreads();
  gate8<0>(a, TB(18)); gate8<1>(a, TB(17)); gate8<2>(a, TB(16)); // L1d1 g13,g14,g15
  #pragma unroll
  for (int r=0;r<8;r++) L[swz(ti | (r<<7))] = a[r];
  __syncthreads();
  #pragma unroll
  for (int r=0;r<8;r++) a[r] = L[swz(r | (ti<<3))];
  __syncthreads();
  gate8<0>(a, TB(31)); gate8<1>(a, TB(30)); gate8<2>(a, TB(29)); // L1d1 g0,g1,g2
  #pragma unroll
  for (int r=0;r<8;r++) L[swz(r | (ti<<3))] = a[r];
  __syncthreads();
  #pragma unroll
  for (int r=0;r<8;r++) a[r] = L[swz((ti&7) | (r<<3) | ((ti>>3)<<6))];
  gate8<0>(a, TB(28));                                           // L1d1 g3
  #pragma unroll
  for (int r=0;r<8;r++) st[bb | p2I((ti&7) | (r<<3) | ((ti>>3)<<6), o)] = a[r];

  gbar(bar+1);

  // ======== phase 3: L1d1 on g4..g9, D1. inner = g0..9, outer o = g10..15 ========
  #pragma unroll
  for (int r=0;r<8;r++) a[r] = st[hi10 | (unsigned)((ti&15) | (r<<4) | ((ti>>4)<<7))];
  gate8<0>(a, TB(27)); gate8<1>(a, TB(26)); gate8<2>(a, TB(25)); // L1d1 g4,g5,g6
  #pragma unroll
  for (int r=0;r<8;r++) L[swz((ti&15) | (r<<4) | ((ti>>4)<<7))] = a[r];
  __syncthreads();
  #pragma unroll
  for (int r=0;r<8;r++) a[r] = L[swz(ti | (r<<7))];
  gate8<0>(a, TB(24)); gate8<1>(a, TB(23)); gate8<2>(a, TB(22)); // L1d1 g7,g8,g9
  diag8<16,16, (1u<<7),(1u<<8),(1u<<9)>(a, tbs, (unsigned)ti | ((unsigned)o<<10)); // D1
  #pragma unroll
  for (int r=0;r<8;r++) st[hi10 | (unsigned)(ti | (r<<7))] = a[r];

  gbar(bar+2);

  // ======== phase 4: sigma1(fused gather), L2..L4, measure ========
  const unsigned og = ((unsigned)(o&1)<<4) | ((unsigned)(o&2)<<5) | ((unsigned)(o&4)<<6)
                    | ((unsigned)(o&8)<<7) | ((unsigned)(o&16)<<8) | ((unsigned)(o&32)<<9);
  #pragma unroll
  for (int r=0;r<8;r++){
    unsigned I = p4I(p4_jA(ti,r), og);
    unsigned s1 = I ^ ((I & 0xAAAAu) >> 1);    // pool-1 CNOT permutation (involution)
    a[r] = st[bb | s1];
  }
  gate8<0>(a, TB(34)); gate8<1>(a, TB(33)); gate8<2>(a, TB(32)); // L2d0 g11,g13,g15
  #pragma unroll
  for (int r=0;r<8;r++) L[swz(p4_jA(ti,r))] = a[r];
  __syncthreads();
  #pragma unroll
  for (int r=0;r<8;r++) a[r] = L[swz(p4_jB(ti,r))];
  __syncthreads();
  gate8<0>(a, TB(37)); gate8<1>(a, TB(36)); gate8<2>(a, TB(35)); // L2d0 g5,g7,g9
  #pragma unroll
  for (int r=0;r<8;r++) L[swz(p4_jB(ti,r))] = a[r];
  __syncthreads();
  #pragma unroll
  for (int r=0;r<8;r++) a[r] = L[swz(p4_jC(ti,r))];
  __syncthreads();
  gate8<0>(a, TB(39)); gate8<1>(a, TB(38));                      // L2d0 g1,g3
  diag8<32,8, 2u,8u,128u>(a, tbs, p4I(p4_jC(ti,0), og));         // D2_0
  gate8<0>(a, TB(47)); gate8<1>(a, TB(46)); gate8<2>(a, TB(44)); // L2d1 g1,g3,g7
  #pragma unroll
  for (int r=0;r<8;r++) L[swz(p4_jC(ti,r))] = a[r];
  __syncthreads();
  #pragma unroll
  for (int r=0;r<8;r++) a[r] = L[swz(p4_jD(ti,r))];
  __syncthreads();
  gate8<0>(a, TB(45)); gate8<1>(a, TB(43)); gate8<2>(a, TB(41)); // L2d1 g5,g9,g13
  #pragma unroll
  for (int r=0;r<8;r++) L[swz(p4_jD(ti,r))] = a[r];
  __syncthreads();
  #pragma unroll
  for (int r=0;r<8;r++) a[r] = L[swz(p4_jA(ti,r))];
  __syncthreads();
  gate8<0>(a, TB(42)); gate8<2>(a, TB(40));                      // L2d1 g11,g15
  diag8<40,8, (1u<<11),(1u<<13),(1u<<15)>(a, tbs, p4I(p4_jA(ti,0), og)); // D2_1
  cnot8<2,1>(a);                                                 // sigma2: CNOT(g15->g13)
  gate8<2>(a, TB(48));                                           // L3d0 g15
  #pragma unroll
  for (int r=0;r<8;r++) L[swz(p4_jA(ti,r))] = a[r];
  __syncthreads();
  #pragma unroll
  for (int r=0;r<8;r++) a[r] = L[swz(p4_jF(ti,r))];
  __syncthreads();
  cnot8<1,0>(a);                                                 // sigma2: CNOT(g11->g9)
  gate8<1>(a, TB(49));                                           // L3d0 g11
  #pragma unroll
  for (int r=0;r<8;r++) L[swz(p4_jF(ti,r))] = a[r];
  __syncthreads();
  #pragma unroll
  for (int r=0;r<8;r++) a[r] = L[swz(p4_jG(ti,r))];
  __syncthreads();
  cnot8<1,0>(a);                                                 // sigma2: CNOT(g7->g5)
  gate8<1>(a, TB(50));                                           // L3d0 g7
  #pragma unroll
  for (int r=0;r<8;r++) L[swz(p4_jG(ti,r))] = a[r];
  __syncthreads();
  #pragma unroll
  for (int r=0;r<8;r++) a[r] = L[swz(p4_jC(ti,r))];
  __syncthreads();
  cnot8<1,0>(a);                                                 // sigma2: CNOT(g3->g1)
  gate8<1>(a, TB(51));                                           // L3d0 g3
  diag8<48,4, 2u,8u,128u>(a, tbs, p4I(p4_jC(ti,0), og));         // D3_0
  gate8<1>(a, TB(55)); gate8<2>(a, TB(54));                      // L3d1 g3,g7
  #pragma unroll
  for (int r=0;r<8;r++) L[swz(p4_jC(ti,r))] = a[r];
  __syncthreads();
  #pragma unroll
  for (int r=0;r<8;r++) a[r] = L[swz(p4_jA(ti,r))];
  __syncthreads();
  gate8<0>(a, TB(53)); gate8<2>(a, TB(52));                      // L3d1 g11,g15
  diag8<52,4, (1u<<11),(1u<<13),(1u<<15)>(a, tbs, p4I(p4_jA(ti,0), og)); // D3_1
  cnot8<2,0>(a);                                                 // sigma3: CNOT(g15->g11)
  gate8<2>(a, TB(56));                                           // L4d0 g15
  #pragma unroll
  for (int r=0;r<8;r++) L[swz(p4_jA(ti,r))] = a[r];
  __syncthreads();
  #pragma unroll
  for (int r=0;r<8;r++) a[r] = L[swz(p4_jJ(ti,r))];
  cnot8<1,0>(a);                                                 // sigma3: CNOT(g7->g3)
  gate8<1>(a, TB(57));                                           // L4d0 g7
  diag8<56,2, 8u,128u,(1u<<15)>(a, tbs, p4I(p4_jJ(ti,0), og));   // D4_0
  gate8<2>(a, TB(58));                                           // L4d1 g15
  // sigma4, D4_1, L4d1(g7) dropped: invariant for the g15 marginal.
  float s = 0.f;
  #pragma unroll
  for (int r=0;r<8;r++){
    float w = a[r].x*a[r].x + a[r].y*a[r].y;
    s += (r & 4) ? -w : w;
  }
  #pragma unroll
  for (int off=32; off>0; off>>=1) s += __shfl_down(s, off);
  if ((t & 63) == 0) red[t>>6] = s;
  __syncthreads();
  if (ti == 0) atomicAdd(out + batch, red[(t>>6)] + red[(t>>6)+1]);
}

extern "C" void kernel_launch(void* const* d_in, const int* in_sizes, int n_in,
                              void* d_out, int out_size, void* d_ws, size_t ws_size,
                              hipStream_t stream) {
  const float* xre = (const float*)d_in[0];
  const float* xim = (const float*)d_in[1];
  const float* p0  = (const float*)d_in[2];
  const float* p1  = (const float*)d_in[3];
  const float* p2  = (const float*)d_in[4];
  const float* p3  = (const float*)d_in[5];
  float* out = (float*)d_out;
  float2* st = (float2*)d_ws;                                   // 8 MB state
  unsigned* bar = (unsigned*)((char*)d_ws + (8u<<20));          // 3 barrier counters

  hipMemsetAsync(bar, 0, 3*sizeof(unsigned), stream);
  hipMemsetAsync(out, 0, 16*sizeof(float), stream);
  k_fused<<<dim3(NBLK), dim3(256), 0, stream>>>(xre, xim, p0, p1, p2, p3, st, bar, out);
}

// Round 6
// 289.346 us; speedup vs baseline: 1.1465x; 1.1465x over previous
//
#include <hip/hip_runtime.h>

// Quantum conv circuit, 16 qubits, batch 16.
// Round 6: persistent single kernel (round-5 structure, verified at absmax 3.05e-5),
//   with barrier surgery: device-scope fences are now WAVE-SCALAR (thread 0 only;
//   round 5 ran the acquire fence in all 2048 waves -> serialized buffer_inv storms),
//   spin backoff s_sleep(16), and out[] zeroed in-kernel (one fewer dispatch).
// 512 blocks x 256 threads (2 tiles/block), co-resident (LDS 18.9KB, lb(256,2)).
// State: float2[16][65536] at d_ws; barrier counters at d_ws + 8MB (memset each call).
// Bit convention: wire w <-> flat-index bit p = 15-w.
// Gate index: L1d0(p)=15-p, L1d1(p)=16+(15-p), L2d0(p)=32+(15-p)/2, L2d1(p)=40+(15-p)/2,
//             L3d0(p)=48+(15-p)/4, L3d1(p)=52+(15-p)/4, L4d0(p)=56+(15-p)/8, L4d1(p)=58+(15-p)/8.

#define DEV __device__ __forceinline__
#define TB(i) (tbs + (i)*8)

#define NBLK 512u

__device__ static const unsigned char G_CP[60] = {
  15,14,13,12,11,10,9,8,7,6,5,4,3,2,1,0,
  15,14,13,12,11,10,9,8,7,6,5,4,3,2,1,0,
  15,13,11,9,7,5,3,1,
  15,13,11,9,7,5,3,1,
  15,11,7,3,
  15,11,7,3,
  15,7,
  15,7
};
__device__ static const unsigned char G_CQ[60] = {
  14,13,12,11,10,9,8,7,6,5,4,3,2,1,0,15,
  14,13,12,11,10,9,8,7,6,5,4,3,2,1,0,15,
  13,11,9,7,5,3,1,15,
  13,11,9,7,5,3,1,15,
  11,7,3,15,
  11,7,3,15,
  7,15,
  7,15
};

DEV float2 F2(float x, float y){ float2 r; r.x = x; r.y = y; return r; }
DEV float2 cmulf(float2 a, float2 b){ return F2(a.x*b.x - a.y*b.y, a.x*b.y + a.y*b.x); }
// XOR bank swizzle on float2 slot index (32 banks = 16 float2 columns); maps [0,1024)->[0,1024).
DEV int swz(int j){ return j ^ ((j>>4)&15) ^ ((j>>6)&15); }

// Device-scope grid barrier (persistent-kernel). All cache-maintenance (threadfence)
// confined to thread 0: __syncthreads() has already drained every wave's stores to the
// XCD L2; one buffer_wbl2 (release) / buffer_inv (acquire) per BLOCK suffices and
// avoids the per-wave fence storm that serialized round 5.
DEV void gbar(unsigned* cnt){
  __syncthreads();
  if (threadIdx.x == 0){
    __threadfence();   // release: write back this XCD's dirty L2 lines
    __hip_atomic_fetch_add(cnt, 1u, __ATOMIC_RELEASE, __HIP_MEMORY_SCOPE_AGENT);
    while (__hip_atomic_load(cnt, __ATOMIC_RELAXED, __HIP_MEMORY_SCOPE_AGENT) < NBLK){
      __builtin_amdgcn_s_sleep(16);   // ~1k cycles between polls: low atomic traffic
    }
    __threadfence();   // acquire: invalidate this CU's L1 + XCD's L2 before reads
  }
  __syncthreads();
}

// 2x2 unitary on register slot bit B of a[8].
template<int B>
DEV void gate8(float2* a, const float* g){
  float u00r=g[0],u00i=g[1],u01r=g[2],u01i=g[3],u10r=g[4],u10i=g[5],u11r=g[6],u11i=g[7];
  #pragma unroll
  for (int m=0; m<4; m++){
    int i0 = ((m>>B)<<(B+1)) | (m & ((1<<B)-1));
    int i1 = i0 | (1<<B);
    float2 x0=a[i0], x1=a[i1];
    a[i0] = F2(u00r*x0.x - u00i*x0.y + u01r*x1.x - u01i*x1.y,
               u00r*x0.y + u00i*x0.x + u01r*x1.y + u01i*x1.x);
    a[i1] = F2(u10r*x0.x - u10i*x0.y + u11r*x1.x - u11i*x1.y,
               u10r*x0.y + u10i*x0.x + u11r*x1.y + u11i*x1.x);
  }
}

template<int CB,int TBIT>
DEV void cnot8(float2* a){
  #pragma unroll
  for (int r=0; r<8; r++){
    if ( ((r>>CB)&1)==1 && ((r>>TBIT)&1)==0 ){
      float2 tmp = a[r]; a[r] = a[r | (1<<TBIT)]; a[r | (1<<TBIT)] = tmp;
    }
  }
}

// RZZ diagonal round, couplings [C0,C0+N). Ib = global 16-bit index with reg bits = 0.
template<int C0,int N,unsigned M0,unsigned M1,unsigned M2>
DEV void diag8(float2* a, const float* tbs, unsigned Ib){
  const unsigned regmask = M0|M1|M2;
  float2 F0 = F2(1.f, 0.f);
  #pragma unroll
  for (int k=0; k<N; k++){
    const int p = G_CP[C0+k], q = G_CQ[C0+k];
    if ( !(((1u<<p)|(1u<<q)) & regmask) ){
      float c = tbs[480 + 2*(C0+k)], s = tbs[481 + 2*(C0+k)];
      unsigned x = ((Ib>>p) ^ (Ib>>q)) & 1u;
      F0 = cmulf(F0, F2(c, x ? s : -s));
    }
  }
  #pragma unroll
  for (int r=0; r<8; r++){
    unsigned Ir = Ib ^ ((r&1)?M0:0u) ^ ((r&2)?M1:0u) ^ ((r&4)?M2:0u);
    float2 ph = F0;
    #pragma unroll
    for (int k=0; k<N; k++){
      const int p = G_CP[C0+k], q = G_CQ[C0+k];
      if ( ((1u<<p)|(1u<<q)) & regmask ){
        float c = tbs[480 + 2*(C0+k)], s = tbs[481 + 2*(C0+k)];
        unsigned x = ((Ir>>p) ^ (Ir>>q)) & 1u;
        ph = cmulf(ph, F2(c, x ? s : -s));
      }
    }
    a[r] = cmulf(a[r], ph);
  }
}

// index helpers — verbatim from round-2 (correctness-verified at absmax 3.05e-5)
DEV unsigned p2I(int j, int o){ return (unsigned)((j&15) | (o<<4) | ((j>>4)<<10)); }
DEV unsigned p4I(int j, unsigned og){
  return (unsigned)( (j&15) | (((j>>4)&1)<<5) | (((j>>5)&1)<<7) | (((j>>6)&1)<<9)
                   | (((j>>7)&1)<<11) | (((j>>8)&1)<<13) | (((j>>9)&1)<<15) ) | og;
}
DEV int p4_jA(int t,int r){ return t | (r<<7); }                                   // slots g11,g13,g15
DEV int p4_jB(int t,int r){ return (t&15) | (r<<4) | ((t>>4)<<7); }                // slots g5,g7,g9
DEV int p4_jC(int t,int r){ return (t&1) | ((r&1)<<1) | (((t>>1)&1)<<2) | (((r>>1)&1)<<3)
                                  | (((t>>2)&1)<<4) | (((r>>2)&1)<<5) | ((t>>3)<<6); } // slots g1,g3,g7
DEV int p4_jD(int t,int r){ return (t&15) | ((r&1)<<4) | (((t>>4)&1)<<5) | (((r>>1)&1)<<6)
                                  | (((t>>5)&1)<<7) | (((r>>2)&1)<<8) | ((t>>6)<<9); } // slots g5,g9,g13
DEV int p4_jF(int t,int r){ return (t&63) | ((r&1)<<6) | (((r>>1)&1)<<7) | (((t>>6)&1)<<8) | ((r>>2)<<9); } // g9,g11,g15
DEV int p4_jG(int t,int r){ return (t&15) | ((r&3)<<4) | (((t>>4)&7)<<6) | ((r>>2)<<9); } // slots g5,g7,g15
DEV int p4_jJ(int t,int r){ return (t&7) | ((r&1)<<3) | (((t>>3)&1)<<4) | (((r>>1)&1)<<5)
                                  | (((t>>4)&7)<<6) | ((r>>2)<<9); }               // slots g3,g7,g15

__global__ __launch_bounds__(256, 2)
void k_fused(const float* __restrict__ xre, const float* __restrict__ xim,
             const float* __restrict__ p0, const float* __restrict__ p1,
             const float* __restrict__ p2, const float* __restrict__ p3,
             float2* __restrict__ st, unsigned* __restrict__ bar,
             float* __restrict__ out){
  const int t  = threadIdx.x;
  const int ti = t & 127;                       // thread id within tile
  const int half = t >> 7;                      // which tile of this block
  const int tile = (blockIdx.x << 1) | half;    // 0..1023
  const int batch = tile >> 6, o = tile & 63;
  const unsigned bb = (unsigned)batch<<16;
  const unsigned hi10 = bb | ((unsigned)o<<10);
  __shared__ float2 lds[2048];                  // one 1024-slot buffer per half
  __shared__ float tbs[600];
  __shared__ float red[4];
  float2* L = lds + (half<<10);
  float2 a[8];

  // out[] zeroing: block 0 before barrier 1 (ordered before all phase-4 atomicAdds
  // by the barrier chain + release fence). Replaces a host-side memset dispatch.
  if (blockIdx.x == 0 && t < 16) out[t] = 0.f;

  // ---- gate-table build (double precision), per-block ----
  if (t < 60){
    int g = t;
    int d, j, n; const float* P;
    if (g < 32)      { n=16; d=(g>>4)&1; j=g&15; P=p0; }
    else if (g < 48) { n=8;  d=(g>>3)&1; j=g&7;  P=p1; }
    else if (g < 56) { n=4;  d=(g>>2)&1; j=g&3;  P=p2; }
    else             { n=2;  d=(g>>1)&1; j=g&1;  P=p3; }
    int base = 4*j + 4*n*d;
    double th0 = P[base+0], th1 = P[base+1], th2 = P[base+2], th3 = P[base+3];
    double c0 = cos(th0*0.5), s0 = sin(th0*0.5);
    double ca = cos(th1*0.5), sa = sin(th1*0.5);
    double c2 = cos(th2*0.5), s2 = sin(th2*0.5);
    double B00r =  ca*c0, B00i = -sa*c0;
    double B01r = -sa*s0, B01i = -ca*s0;
    double B10r =  sa*s0, B10i = -ca*s0;
    double B11r =  ca*c0, B11i =  sa*c0;
    float* oo = tbs + g*8;
    oo[0]=(float)(c2*B00r + s2*B10i); oo[1]=(float)(c2*B00i - s2*B10r);
    oo[2]=(float)(c2*B01r + s2*B11i); oo[3]=(float)(c2*B01i - s2*B11r);
    oo[4]=(float)(s2*B00i + c2*B10r); oo[5]=(float)(-s2*B00r + c2*B10i);
    oo[6]=(float)(s2*B01i + c2*B11r); oo[7]=(float)(-s2*B01r + c2*B11i);
    tbs[480 + 2*g] = (float)cos(th3*0.5);
    tbs[481 + 2*g] = (float)sin(th3*0.5);
  }
  __syncthreads();

  // ======== phase 1: L1d0 on g0..g9. inner j = g0..9, outer o = g10..15 ========
  {
    unsigned base = hi10 | ((unsigned)ti<<3);
    float4 r0 = *(const float4*)(xre+base), r1 = *(const float4*)(xre+base+4);
    float4 i0 = *(const float4*)(xim+base), i1 = *(const float4*)(xim+base+4);
    a[0]=F2(r0.x,i0.x); a[1]=F2(r0.y,i0.y); a[2]=F2(r0.z,i0.z); a[3]=F2(r0.w,i0.w);
    a[4]=F2(r1.x,i1.x); a[5]=F2(r1.y,i1.y); a[6]=F2(r1.z,i1.z); a[7]=F2(r1.w,i1.w);
  }
  gate8<0>(a, TB(15)); gate8<1>(a, TB(14)); gate8<2>(a, TB(13));
  #pragma unroll
  for (int r=0;r<8;r++) L[swz(r | (ti<<3))] = a[r];
  __syncthreads();
  #pragma unroll
  for (int r=0;r<8;r++) a[r] = L[swz((ti&7) | (r<<3) | ((ti>>3)<<6))];
  __syncthreads();
  gate8<0>(a, TB(12)); gate8<1>(a, TB(11)); gate8<2>(a, TB(10));
  #pragma unroll
  for (int r=0;r<8;r++) L[swz((ti&7) | (r<<3) | ((ti>>3)<<6))] = a[r];
  __syncthreads();
  #pragma unroll
  for (int r=0;r<8;r++) a[r] = L[swz((ti&63) | (r<<6) | ((ti>>6)<<9))];
  __syncthreads();
  gate8<0>(a, TB(9)); gate8<1>(a, TB(8)); gate8<2>(a, TB(7));
  #pragma unroll
  for (int r=0;r<8;r++) L[swz((ti&63) | (r<<6) | ((ti>>6)<<9))] = a[r];
  __syncthreads();
  #pragma unroll
  for (int r=0;r<8;r++) a[r] = L[swz(ti | (r<<7))];
  gate8<2>(a, TB(6));  // g9
  #pragma unroll
  for (int r=0;r<8;r++) st[hi10 | (unsigned)(ti | (r<<7))] = a[r];

  gbar(bar+0);

  // ======== phase 2: L1d0 g10..15, D0, L1d1 on {g0..3, g10..15}. outer o = g4..9 ========
  #pragma unroll
  for (int r=0;r<8;r++) a[r] = st[bb | p2I(ti | (r<<7), o)];
  gate8<0>(a, TB(2)); gate8<1>(a, TB(1)); gate8<2>(a, TB(0));
  #pragma unroll
  for (int r=0;r<8;r++) L[swz(ti | (r<<7))] = a[r];
  __syncthreads();
  #pragma unroll
  for (int r=0;r<8;r++) a[r] = L[swz((ti&15) | (r<<4) | ((ti>>4)<<7))];
  __syncthreads();
  gate8<0>(a, TB(5)); gate8<1>(a, TB(4)); gate8<2>(a, TB(3));     // L1d0 g10,g11,g12
  diag8<0,16, (1u<<10),(1u<<11),(1u<<12)>(a, tbs, p2I((ti&15) | ((ti>>4)<<7), o));  // D0
  gate8<0>(a, TB(21)); gate8<1>(a, TB(20)); gate8<2>(a, TB(19));  // L1d1 g10,g11,g12
  #pragma unroll
  for (int r=0;r<8;r++) L[swz((ti&15) | (r<<4) | ((ti>>4)<<7))] = a[r];
  __syncthreads();
  #pragma unroll
  for (int r=0;r<8;r++) a[r] = L[swz(ti | (r<<7))];
  __syncthreads();
  gate8<0>(a, TB(18)); gate8<1>(a, TB(17)); gate8<2>(a, TB(16)); // L1d1 g13,g14,g15
  #pragma unroll
  for (int r=0;r<8;r++) L[swz(ti | (r<<7))] = a[r];
  __syncthreads();
  #pragma unroll
  for (int r=0;r<8;r++) a[r] = L[swz(r | (ti<<3))];
  __syncthreads();
  gate8<0>(a, TB(31)); gate8<1>(a, TB(30)); gate8<2>(a, TB(29)); // L1d1 g0,g1,g2
  #pragma unroll
  for (int r=0;r<8;r++) L[swz(r | (ti<<3))] = a[r];
  __syncthreads();
  #pragma unroll
  for (int r=0;r<8;r++) a[r] = L[swz((ti&7) | (r<<3) | ((ti>>3)<<6))];
  gate8<0>(a, TB(28));                                           // L1d1 g3
  #pragma unroll
  for (int r=0;r<8;r++) st[bb | p2I((ti&7) | (r<<3) | ((ti>>3)<<6), o)] = a[r];

  gbar(bar+1);

  // ======== phase 3: L1d1 on g4..g9, D1. inner = g0..9, outer o = g10..15 ========
  #pragma unroll
  for (int r=0;r<8;r++) a[r] = st[hi10 | (unsigned)((ti&15) | (r<<4) | ((ti>>4)<<7))];
  gate8<0>(a, TB(27)); gate8<1>(a, TB(26)); gate8<2>(a, TB(25)); // L1d1 g4,g5,g6
  #pragma unroll
  for (int r=0;r<8;r++) L[swz((ti&15) | (r<<4) | ((ti>>4)<<7))] = a[r];
  __syncthreads();
  #pragma unroll
  for (int r=0;r<8;r++) a[r] = L[swz(ti | (r<<7))];
  gate8<0>(a, TB(24)); gate8<1>(a, TB(23)); gate8<2>(a, TB(22)); // L1d1 g7,g8,g9
  diag8<16,16, (1u<<7),(1u<<8),(1u<<9)>(a, tbs, (unsigned)ti | ((unsigned)o<<10)); // D1
  #pragma unroll
  for (int r=0;r<8;r++) st[hi10 | (unsigned)(ti | (r<<7))] = a[r];

  gbar(bar+2);

  // ======== phase 4: sigma1(fused gather), L2..L4, measure ========
  const unsigned og = ((unsigned)(o&1)<<4) | ((unsigned)(o&2)<<5) | ((unsigned)(o&4)<<6)
                    | ((unsigned)(o&8)<<7) | ((unsigned)(o&16)<<8) | ((unsigned)(o&32)<<9);
  #pragma unroll
  for (int r=0;r<8;r++){
    unsigned I = p4I(p4_jA(ti,r), og);
    unsigned s1 = I ^ ((I & 0xAAAAu) >> 1);    // pool-1 CNOT permutation (involution)
    a[r] = st[bb | s1];
  }
  gate8<0>(a, TB(34)); gate8<1>(a, TB(33)); gate8<2>(a, TB(32)); // L2d0 g11,g13,g15
  #pragma unroll
  for (int r=0;r<8;r++) L[swz(p4_jA(ti,r))] = a[r];
  __syncthreads();
  #pragma unroll
  for (int r=0;r<8;r++) a[r] = L[swz(p4_jB(ti,r))];
  __syncthreads();
  gate8<0>(a, TB(37)); gate8<1>(a, TB(36)); gate8<2>(a, TB(35)); // L2d0 g5,g7,g9
  #pragma unroll
  for (int r=0;r<8;r++) L[swz(p4_jB(ti,r))] = a[r];
  __syncthreads();
  #pragma unroll
  for (int r=0;r<8;r++) a[r] = L[swz(p4_jC(ti,r))];
  __syncthreads();
  gate8<0>(a, TB(39)); gate8<1>(a, TB(38));                      // L2d0 g1,g3
  diag8<32,8, 2u,8u,128u>(a, tbs, p4I(p4_jC(ti,0), og));         // D2_0
  gate8<0>(a, TB(47)); gate8<1>(a, TB(46)); gate8<2>(a, TB(44)); // L2d1 g1,g3,g7
  #pragma unroll
  for (int r=0;r<8;r++) L[swz(p4_jC(ti,r))] = a[r];
  __syncthreads();
  #pragma unroll
  for (int r=0;r<8;r++) a[r] = L[swz(p4_jD(ti,r))];
  __syncthreads();
  gate8<0>(a, TB(45)); gate8<1>(a, TB(43)); gate8<2>(a, TB(41)); // L2d1 g5,g9,g13
  #pragma unroll
  for (int r=0;r<8;r++) L[swz(p4_jD(ti,r))] = a[r];
  __syncthreads();
  #pragma unroll
  for (int r=0;r<8;r++) a[r] = L[swz(p4_jA(ti,r))];
  __syncthreads();
  gate8<0>(a, TB(42)); gate8<2>(a, TB(40));                      // L2d1 g11,g15
  diag8<40,8, (1u<<11),(1u<<13),(1u<<15)>(a, tbs, p4I(p4_jA(ti,0), og)); // D2_1
  cnot8<2,1>(a);                                                 // sigma2: CNOT(g15->g13)
  gate8<2>(a, TB(48));                                           // L3d0 g15
  #pragma unroll
  for (int r=0;r<8;r++) L[swz(p4_jA(ti,r))] = a[r];
  __syncthreads();
  #pragma unroll
  for (int r=0;r<8;r++) a[r] = L[swz(p4_jF(ti,r))];
  __syncthreads();
  cnot8<1,0>(a);                                                 // sigma2: CNOT(g11->g9)
  gate8<1>(a, TB(49));                                           // L3d0 g11
  #pragma unroll
  for (int r=0;r<8;r++) L[swz(p4_jF(ti,r))] = a[r];
  __syncthreads();
  #pragma unroll
  for (int r=0;r<8;r++) a[r] = L[swz(p4_jG(ti,r))];
  __syncthreads();
  cnot8<1,0>(a);                                                 // sigma2: CNOT(g7->g5)
  gate8<1>(a, TB(50));                                           // L3d0 g7
  #pragma unroll
  for (int r=0;r<8;r++) L[swz(p4_jG(ti,r))] = a[r];
  __syncthreads();
  #pragma unroll
  for (int r=0;r<8;r++) a[r] = L[swz(p4_jC(ti,r))];
  __syncthreads();
  cnot8<1,0>(a);                                                 // sigma2: CNOT(g3->g1)
  gate8<1>(a, TB(51));                                           // L3d0 g3
  diag8<48,4, 2u,8u,128u>(a, tbs, p4I(p4_jC(ti,0), og));         // D3_0
  gate8<1>(a, TB(55)); gate8<2>(a, TB(54));                      // L3d1 g3,g7
  #pragma unroll
  for (int r=0;r<8;r++) L[swz(p4_jC(ti,r))] = a[r];
  __syncthreads();
  #pragma unroll
  for (int r=0;r<8;r++) a[r] = L[swz(p4_jA(ti,r))];
  __syncthreads();
  gate8<0>(a, TB(53)); gate8<2>(a, TB(52));                      // L3d1 g11,g15
  diag8<52,4, (1u<<11),(1u<<13),(1u<<15)>(a, tbs, p4I(p4_jA(ti,0), og)); // D3_1
  cnot8<2,0>(a);                                                 // sigma3: CNOT(g15->g11)
  gate8<2>(a, TB(56));                                           // L4d0 g15
  #pragma unroll
  for (int r=0;r<8;r++) L[swz(p4_jA(ti,r))] = a[r];
  __syncthreads();
  #pragma unroll
  for (int r=0;r<8;r++) a[r] = L[swz(p4_jJ(ti,r))];
  cnot8<1,0>(a);                                                 // sigma3: CNOT(g7->g3)
  gate8<1>(a, TB(57));                                           // L4d0 g7
  diag8<56,2, 8u,128u,(1u<<15)>(a, tbs, p4I(p4_jJ(ti,0), og));   // D4_0
  gate8<2>(a, TB(58));                                           // L4d1 g15
  // sigma4, D4_1, L4d1(g7) dropped: invariant for the g15 marginal.
  float s = 0.f;
  #pragma unroll
  for (int r=0;r<8;r++){
    float w = a[r].x*a[r].x + a[r].y*a[r].y;
    s += (r & 4) ? -w : w;
  }
  #pragma unroll
  for (int off=32; off>0; off>>=1) s += __shfl_down(s, off);
  if ((t & 63) == 0) red[t>>6] = s;
  __syncthreads();
  if (ti == 0) atomicAdd(out + batch, red[(t>>6)] + red[(t>>6)+1]);
}

extern "C" void kernel_launch(void* const* d_in, const int* in_sizes, int n_in,
                              void* d_out, int out_size, void* d_ws, size_t ws_size,
                              hipStream_t stream) {
  const float* xre = (const float*)d_in[0];
  const float* xim = (const float*)d_in[1];
  const float* p0  = (const float*)d_in[2];
  const float* p1  = (const float*)d_in[3];
  const float* p2  = (const float*)d_in[4];
  const float* p3  = (const float*)d_in[5];
  float* out = (float*)d_out;
  float2* st = (float2*)d_ws;                                   // 8 MB state
  unsigned* bar = (unsigned*)((char*)d_ws + (8u<<20));          // 3 barrier counters

  hipMemsetAsync(bar, 0, 3*sizeof(unsigned), stream);
  k_fused<<<dim3(NBLK), dim3(256), 0, stream>>>(xre, xim, p0, p1, p2, p3, st, bar, out);
}

// Round 7
// 114.257 us; speedup vs baseline: 2.9034x; 2.5324x over previous
//
#include <hip/hip_runtime.h>

// Quantum conv circuit, 16 qubits, batch 16.
// Round 7: back to multi-dispatch (persistent-kernel barriers cost ~150 us; dead end).
//   4 passes over 2048-amp tiles (11 inner bits), 512 blocks x 512 threads,
//   4 amps/thread (2 reg bits) -> 4096 waves = 16 waves/CU (2x round 2).
//   sigma1 fused into pass-4 global gather; sigma2/sigma3 remainders folded into
//   LDS-exchange read indices. Gate coeffs read from global tbl (uniform -> s_load).
// Layout: st = float2[16][65536] at d_ws; tbl (600 floats) at d_ws + 8MB.
// Bit convention: wire w <-> flat-index bit p = 15-w.
// Gate index: L1d0(p)=15-p, L1d1(p)=16+(15-p), L2d0(p)=32+(15-p)/2, L2d1(p)=40+(15-p)/2,
//             L3d0(p)=48+(15-p)/4, L3d1(p)=52+(15-p)/4, L4d0(p)=56+(15-p)/8, L4d1(p)=58+(15-p)/8.

#define DEV __device__ __forceinline__
#define TBL(i) (tbl + (i)*8)

__device__ static const unsigned char G_CP[60] = {
  15,14,13,12,11,10,9,8,7,6,5,4,3,2,1,0,
  15,14,13,12,11,10,9,8,7,6,5,4,3,2,1,0,
  15,13,11,9,7,5,3,1,
  15,13,11,9,7,5,3,1,
  15,11,7,3,
  15,11,7,3,
  15,7,
  15,7
};
__device__ static const unsigned char G_CQ[60] = {
  14,13,12,11,10,9,8,7,6,5,4,3,2,1,0,15,
  14,13,12,11,10,9,8,7,6,5,4,3,2,1,0,15,
  13,11,9,7,5,3,1,15,
  13,11,9,7,5,3,1,15,
  11,7,3,15,
  11,7,3,15,
  7,15,
  7,15
};

DEV float2 F2(float x, float y){ float2 r; r.x = x; r.y = y; return r; }
DEV float2 cmulf(float2 a, float2 b){ return F2(a.x*b.x - a.y*b.y, a.x*b.y + a.y*b.x); }
// XOR bank swizzle on float2 slot index, 2048 slots (32 banks = 16 float2 columns).
DEV int swz(int j){ return j ^ ((j>>4)&15) ^ ((j>>8)&15); }

// slot s (2 bits) -> inner bits A (s bit0), B (s bit1); t's 9 bits fill the rest ascending.
template<int A,int B>
DEV int mapj(int t, int s){
  int j = ((s&1)<<A) | (((s>>1)&1)<<B);
  int ti = 0;
  #pragma unroll
  for (int b=0;b<11;b++){
    if (b!=A && b!=B){ j |= ((t>>ti)&1)<<b; ti++; }
  }
  return j;
}

// 2x2 unitary on slot bit SB of a[4]. g uniform -> scalar loads.
template<int SB>
DEV void gate4(float2* a, const float* __restrict__ g){
  float u00r=g[0],u00i=g[1],u01r=g[2],u01i=g[3],u10r=g[4],u10i=g[5],u11r=g[6],u11i=g[7];
  #pragma unroll
  for (int m=0;m<2;m++){
    int i0 = (SB==0) ? (m<<1) : m;
    int i1 = i0 | (1<<SB);
    float2 x0=a[i0], x1=a[i1];
    a[i0] = F2(u00r*x0.x - u00i*x0.y + u01r*x1.x - u01i*x1.y,
               u00r*x0.y + u00i*x0.x + u01r*x1.y + u01i*x1.x);
    a[i1] = F2(u10r*x0.x - u10i*x0.y + u11r*x1.x - u11i*x1.y,
               u10r*x0.y + u10i*x0.x + u11r*x1.y + u11i*x1.x);
  }
}

// RZZ round, couplings [C0,C0+N). Ib = global 16-bit index with the two reg bits zeroed.
// M0/M1 = global masks of slot bits 0/1.
template<int C0,int N,unsigned M0,unsigned M1>
DEV void diag4(float2* a, const float* __restrict__ tbl, unsigned Ib){
  const unsigned regmask = M0|M1;
  float2 F0 = F2(1.f, 0.f);
  #pragma unroll
  for (int k=0;k<N;k++){
    const int p = G_CP[C0+k], q = G_CQ[C0+k];
    if ( !(((1u<<p)|(1u<<q)) & regmask) ){
      float c = tbl[480 + 2*(C0+k)], s = tbl[481 + 2*(C0+k)];
      unsigned x = ((Ib>>p) ^ (Ib>>q)) & 1u;
      F0 = cmulf(F0, F2(c, x ? s : -s));
    }
  }
  #pragma unroll
  for (int r=0;r<4;r++){
    unsigned Ir = Ib ^ ((r&1)?M0:0u) ^ ((r&2)?M1:0u);
    float2 ph = F0;
    #pragma unroll
    for (int k=0;k<N;k++){
      const int p = G_CP[C0+k], q = G_CQ[C0+k];
      if ( ((1u<<p)|(1u<<q)) & regmask ){
        float c = tbl[480 + 2*(C0+k)], s = tbl[481 + 2*(C0+k)];
        unsigned x = ((Ir>>p) ^ (Ir>>q)) & 1u;
        ph = cmulf(ph, F2(c, x ? s : -s));
      }
    }
    a[r] = cmulf(a[r], ph);
  }
}

// ---- global index maps ----
// P1/P3: inner j0..10 = g0..g10, outer o = g11..15
DEV unsigned Ia(int j, int o){ return (unsigned)(j | (o<<11)); }
// P2: inner (j0..5)=(g0..g5), (j6..10)=(g11..15); outer o = g6..g10
DEV unsigned Ib2(int j, int o){ return (unsigned)((j&63) | (o<<6) | ((j>>6)<<11)); }
// P4: inner j0..10 -> g{1,3,5,6,7,8,9,10,11,13,15}; outer o0..4 -> g{0,2,4,12,14}
DEV unsigned Ic(int j, int o){
  return (unsigned)( ((j&1)<<1) | (((j>>1)&1)<<3) | (((j>>2)&1)<<5)
       | (((j>>3)&63)<<6) | (((j>>9)&1)<<13) | (((j>>10)&1)<<15)
       | (o&1) | (((o>>1)&1)<<2) | (((o>>2)&1)<<4) | (((o>>3)&1)<<12) | (((o>>4)&1)<<14) );
}
// sigma2 remainder: (g11->g9),(g7->g5),(g3->g1) = inner (j8->j6),(j4->j2),(j1->j0)
DEV int s2perm(int j){ return j ^ (((j>>8)&1)<<6) ^ (((j>>4)&1)<<2) ^ (((j>>1)&1)<<0); }
// sigma3: (g15->g11),(g7->g3) = (j10->j8),(j4->j1)
DEV int s3perm(int j){ return j ^ (((j>>10)&1)<<8) ^ (((j>>4)&1)<<1); }

// ---------- setup: U = RX(t2)*RZ(t1)*RX(t0) in double + couplings; zero out ----------
__global__ void k_setup(const float* __restrict__ p0, const float* __restrict__ p1,
                        const float* __restrict__ p2, const float* __restrict__ p3,
                        float* __restrict__ tbl, float* __restrict__ out){
  int g = threadIdx.x;
  if (g < 16) out[g] = 0.f;
  if (g >= 60) return;
  int d, j, n; const float* P;
  if (g < 32)      { n=16; d=(g>>4)&1; j=g&15; P=p0; }
  else if (g < 48) { n=8;  d=(g>>3)&1; j=g&7;  P=p1; }
  else if (g < 56) { n=4;  d=(g>>2)&1; j=g&3;  P=p2; }
  else             { n=2;  d=(g>>1)&1; j=g&1;  P=p3; }
  int base = 4*j + 4*n*d;
  double th0 = P[base+0], th1 = P[base+1], th2 = P[base+2], th3 = P[base+3];
  double c0 = cos(th0*0.5), s0 = sin(th0*0.5);
  double ca = cos(th1*0.5), sa = sin(th1*0.5);
  double c2 = cos(th2*0.5), s2 = sin(th2*0.5);
  double B00r =  ca*c0, B00i = -sa*c0;
  double B01r = -sa*s0, B01i = -ca*s0;
  double B10r =  sa*s0, B10i = -ca*s0;
  double B11r =  ca*c0, B11i =  sa*c0;
  float* o = tbl + g*8;
  o[0]=(float)(c2*B00r + s2*B10i); o[1]=(float)(c2*B00i - s2*B10r);
  o[2]=(float)(c2*B01r + s2*B11i); o[3]=(float)(c2*B01i - s2*B11r);
  o[4]=(float)(s2*B00i + c2*B10r); o[5]=(float)(-s2*B00r + c2*B10i);
  o[6]=(float)(s2*B01i + c2*B11r); o[7]=(float)(-s2*B01r + c2*B11i);
  tbl[480 + 2*g] = (float)cos(th3*0.5);
  tbl[481 + 2*g] = (float)sin(th3*0.5);
}

// ======== pass 1: L1d0 g0..g10. inner = g0..10, outer = g11..15 ========
__global__ __launch_bounds__(512, 4)
void k_p1(const float* __restrict__ xre, const float* __restrict__ xim,
          const float* __restrict__ tbl, float2* __restrict__ st){
  const int t = threadIdx.x;
  const int batch = blockIdx.x >> 5, o = blockIdx.x & 31;
  const unsigned hi = ((unsigned)batch<<16) | ((unsigned)o<<11);
  __shared__ float2 lds[2][2048];
  float2 a[4];
  { // S1: map(0,1); j = s | (t<<2): float4 loads
    unsigned base = hi | ((unsigned)t<<2);
    float4 re = *(const float4*)(xre + base);
    float4 im = *(const float4*)(xim + base);
    a[0]=F2(re.x,im.x); a[1]=F2(re.y,im.y); a[2]=F2(re.z,im.z); a[3]=F2(re.w,im.w);
  }
  gate4<0>(a, TBL(15)); gate4<1>(a, TBL(14));                   // g0,g1
  #pragma unroll
  for (int s=0;s<4;s++) lds[0][swz(mapj<0,1>(t,s))] = a[s];
  __syncthreads();
  #pragma unroll
  for (int s=0;s<4;s++) a[s] = lds[0][swz(mapj<2,3>(t,s))];
  gate4<0>(a, TBL(13)); gate4<1>(a, TBL(12));                   // g2,g3
  #pragma unroll
  for (int s=0;s<4;s++) lds[1][swz(mapj<2,3>(t,s))] = a[s];
  __syncthreads();
  #pragma unroll
  for (int s=0;s<4;s++) a[s] = lds[1][swz(mapj<4,5>(t,s))];
  gate4<0>(a, TBL(11)); gate4<1>(a, TBL(10));                   // g4,g5
  #pragma unroll
  for (int s=0;s<4;s++) lds[0][swz(mapj<4,5>(t,s))] = a[s];
  __syncthreads();
  #pragma unroll
  for (int s=0;s<4;s++) a[s] = lds[0][swz(mapj<6,7>(t,s))];
  gate4<0>(a, TBL(9)); gate4<1>(a, TBL(8));                     // g6,g7
  #pragma unroll
  for (int s=0;s<4;s++) lds[1][swz(mapj<6,7>(t,s))] = a[s];
  __syncthreads();
  #pragma unroll
  for (int s=0;s<4;s++) a[s] = lds[1][swz(mapj<8,9>(t,s))];
  gate4<0>(a, TBL(7)); gate4<1>(a, TBL(6));                     // g8,g9
  #pragma unroll
  for (int s=0;s<4;s++) lds[0][swz(mapj<8,9>(t,s))] = a[s];
  __syncthreads();
  #pragma unroll
  for (int s=0;s<4;s++) a[s] = lds[0][swz(mapj<0,10>(t,s))];
  gate4<1>(a, TBL(5));                                          // g10 (slot bit 1)
  #pragma unroll
  for (int s=0;s<4;s++) st[hi | (unsigned)mapj<0,10>(t,s)] = a[s];
}

// ======== pass 2: L1d0 g11..15, D0, L1d1 {g0..g5, g11..15}. outer = g6..g10 ========
__global__ __launch_bounds__(512, 4)
void k_p2(const float* __restrict__ tbl, float2* __restrict__ st){
  const int t = threadIdx.x;
  const int batch = blockIdx.x >> 5, o = blockIdx.x & 31;
  const unsigned bb = (unsigned)batch<<16;
  __shared__ float2 lds[2][2048];
  float2 a[4];
  // U1: map(10,9) = (g15,g14)
  #pragma unroll
  for (int s=0;s<4;s++) a[s] = st[bb | Ib2(mapj<10,9>(t,s), o)];
  gate4<0>(a, TBL(0)); gate4<1>(a, TBL(1));                     // L1d0 g15,g14
  #pragma unroll
  for (int s=0;s<4;s++) lds[0][swz(mapj<10,9>(t,s))] = a[s];
  __syncthreads();
  // U2: map(8,7) = (g13,g12)
  #pragma unroll
  for (int s=0;s<4;s++) a[s] = lds[0][swz(mapj<8,7>(t,s))];
  gate4<0>(a, TBL(2)); gate4<1>(a, TBL(3));                     // L1d0 g13,g12
  #pragma unroll
  for (int s=0;s<4;s++) lds[1][swz(mapj<8,7>(t,s))] = a[s];
  __syncthreads();
  // U3: map(6,5) = (g11,g5)
  #pragma unroll
  for (int s=0;s<4;s++) a[s] = lds[1][swz(mapj<6,5>(t,s))];
  gate4<0>(a, TBL(4));                                          // L1d0 g11 -> L1d0 done
  diag4<0,16, (1u<<11),(1u<<5)>(a, tbl, Ib2(mapj<6,5>(t,0), o));// D0
  gate4<0>(a, TBL(20)); gate4<1>(a, TBL(26));                   // L1d1 g11, g5
  #pragma unroll
  for (int s=0;s<4;s++) lds[0][swz(mapj<6,5>(t,s))] = a[s];
  __syncthreads();
  // U4: map(7,8) = (g12,g13)
  #pragma unroll
  for (int s=0;s<4;s++) a[s] = lds[0][swz(mapj<7,8>(t,s))];
  gate4<0>(a, TBL(19)); gate4<1>(a, TBL(18));                   // L1d1 g12,g13
  #pragma unroll
  for (int s=0;s<4;s++) lds[1][swz(mapj<7,8>(t,s))] = a[s];
  __syncthreads();
  // U5: map(9,10) = (g14,g15)
  #pragma unroll
  for (int s=0;s<4;s++) a[s] = lds[1][swz(mapj<9,10>(t,s))];
  gate4<0>(a, TBL(17)); gate4<1>(a, TBL(16));                   // L1d1 g14,g15
  #pragma unroll
  for (int s=0;s<4;s++) lds[0][swz(mapj<9,10>(t,s))] = a[s];
  __syncthreads();
  // U6: map(0,1) = (g0,g1)
  #pragma unroll
  for (int s=0;s<4;s++) a[s] = lds[0][swz(mapj<0,1>(t,s))];
  gate4<0>(a, TBL(31)); gate4<1>(a, TBL(30));                   // L1d1 g0,g1
  #pragma unroll
  for (int s=0;s<4;s++) lds[1][swz(mapj<0,1>(t,s))] = a[s];
  __syncthreads();
  // U7: map(2,3) = (g2,g3)
  #pragma unroll
  for (int s=0;s<4;s++) a[s] = lds[1][swz(mapj<2,3>(t,s))];
  gate4<0>(a, TBL(29)); gate4<1>(a, TBL(28));                   // L1d1 g2,g3
  #pragma unroll
  for (int s=0;s<4;s++) lds[0][swz(mapj<2,3>(t,s))] = a[s];
  __syncthreads();
  // U8: map(4,10) = (g4, g15-spare)
  #pragma unroll
  for (int s=0;s<4;s++) a[s] = lds[0][swz(mapj<4,10>(t,s))];
  gate4<0>(a, TBL(27));                                         // L1d1 g4
  #pragma unroll
  for (int s=0;s<4;s++) st[bb | Ib2(mapj<4,10>(t,s), o)] = a[s];
}

// ======== pass 3: L1d1 g6..g10, D1. inner = g0..10, outer = g11..15 ========
__global__ __launch_bounds__(512, 4)
void k_p3(const float* __restrict__ tbl, float2* __restrict__ st){
  const int t = threadIdx.x;
  const int batch = blockIdx.x >> 5, o = blockIdx.x & 31;
  const unsigned hi = ((unsigned)batch<<16) | ((unsigned)o<<11);
  __shared__ float2 lds[2][2048];
  float2 a[4];
  // W1: map(6,7) = (g6,g7)
  #pragma unroll
  for (int s=0;s<4;s++) a[s] = st[hi | (unsigned)mapj<6,7>(t,s)];
  gate4<0>(a, TBL(25)); gate4<1>(a, TBL(24));                   // L1d1 g6,g7
  #pragma unroll
  for (int s=0;s<4;s++) lds[0][swz(mapj<6,7>(t,s))] = a[s];
  __syncthreads();
  // W2: map(8,9) = (g8,g9)
  #pragma unroll
  for (int s=0;s<4;s++) a[s] = lds[0][swz(mapj<8,9>(t,s))];
  gate4<0>(a, TBL(23)); gate4<1>(a, TBL(22));                   // L1d1 g8,g9
  #pragma unroll
  for (int s=0;s<4;s++) lds[1][swz(mapj<8,9>(t,s))] = a[s];
  __syncthreads();
  // W3: map(0,10) = (g0,g10)
  #pragma unroll
  for (int s=0;s<4;s++) a[s] = lds[1][swz(mapj<0,10>(t,s))];
  gate4<1>(a, TBL(21));                                         // L1d1 g10 -> L1d1 done
  diag4<16,16, 1u,(1u<<10)>(a, tbl, Ia(mapj<0,10>(t,0), o));    // D1
  #pragma unroll
  for (int s=0;s<4;s++) st[hi | (unsigned)mapj<0,10>(t,s)] = a[s];
}

// ======== pass 4: sigma1 gather, L2..L4, measure. inner -> g{1,3,5,6,7,8,9,10,11,13,15} ========
__global__ __launch_bounds__(512, 4)
void k_p4(const float* __restrict__ tbl, float2* __restrict__ st, float* __restrict__ out){
  const int t = threadIdx.x;
  const int batch = blockIdx.x >> 5, o = blockIdx.x & 31;
  const unsigned bb = (unsigned)batch<<16;
  __shared__ float2 lds[2][2048];
  __shared__ float red[8];
  float2 a[4];
  // V1: map(10,9) = (g15,g13); sigma1 fused into gather (controls = odd bits)
  #pragma unroll
  for (int s=0;s<4;s++){
    unsigned I = Ic(mapj<10,9>(t,s), o);
    I ^= (I & 0xAAAAu) >> 1;                                    // pool-1 CNOTs
    a[s] = st[bb | I];
  }
  gate4<0>(a, TBL(32)); gate4<1>(a, TBL(33));                   // L2d0 g15,g13
  #pragma unroll
  for (int s=0;s<4;s++) lds[0][swz(mapj<10,9>(t,s))] = a[s];
  __syncthreads();
  // V2: map(8,6) = (g11,g9)
  #pragma unroll
  for (int s=0;s<4;s++) a[s] = lds[0][swz(mapj<8,6>(t,s))];
  gate4<0>(a, TBL(34)); gate4<1>(a, TBL(35));                   // L2d0 g11,g9
  #pragma unroll
  for (int s=0;s<4;s++) lds[1][swz(mapj<8,6>(t,s))] = a[s];
  __syncthreads();
  // V3: map(4,2) = (g7,g5)
  #pragma unroll
  for (int s=0;s<4;s++) a[s] = lds[1][swz(mapj<4,2>(t,s))];
  gate4<0>(a, TBL(36)); gate4<1>(a, TBL(37));                   // L2d0 g7,g5
  #pragma unroll
  for (int s=0;s<4;s++) lds[0][swz(mapj<4,2>(t,s))] = a[s];
  __syncthreads();
  // V4: map(1,0) = (g3,g1)
  #pragma unroll
  for (int s=0;s<4;s++) a[s] = lds[0][swz(mapj<1,0>(t,s))];
  gate4<0>(a, TBL(38)); gate4<1>(a, TBL(39));                   // L2d0 g3,g1 -> L2d0 done
  diag4<32,8, (1u<<3),(1u<<1)>(a, tbl, Ic(mapj<1,0>(t,0), o));  // D2_0
  gate4<0>(a, TBL(46)); gate4<1>(a, TBL(47));                   // L2d1 g3,g1
  #pragma unroll
  for (int s=0;s<4;s++) lds[1][swz(mapj<1,0>(t,s))] = a[s];
  __syncthreads();
  // V5: map(2,4) = (g5,g7)
  #pragma unroll
  for (int s=0;s<4;s++) a[s] = lds[1][swz(mapj<2,4>(t,s))];
  gate4<0>(a, TBL(45)); gate4<1>(a, TBL(44));                   // L2d1 g5,g7
  #pragma unroll
  for (int s=0;s<4;s++) lds[0][swz(mapj<2,4>(t,s))] = a[s];
  __syncthreads();
  // V6: map(6,8) = (g9,g11)
  #pragma unroll
  for (int s=0;s<4;s++) a[s] = lds[0][swz(mapj<6,8>(t,s))];
  gate4<0>(a, TBL(43)); gate4<1>(a, TBL(42));                   // L2d1 g9,g11
  #pragma unroll
  for (int s=0;s<4;s++) lds[1][swz(mapj<6,8>(t,s))] = a[s];
  __syncthreads();
  // V7: map(9,10) = (g13,g15)
  #pragma unroll
  for (int s=0;s<4;s++) a[s] = lds[1][swz(mapj<9,10>(t,s))];
  gate4<0>(a, TBL(41)); gate4<1>(a, TBL(40));                   // L2d1 g13,g15 -> done
  diag4<40,8, (1u<<13),(1u<<15)>(a, tbl, Ic(mapj<9,10>(t,0), o)); // D2_1
  { float2 tmp=a[2]; a[2]=a[3]; a[3]=tmp; }                     // sigma2: CNOT(g15->g13)
  gate4<1>(a, TBL(48));                                         // L3d0 g15
  #pragma unroll
  for (int s=0;s<4;s++) lds[0][swz(mapj<9,10>(t,s))] = a[s];
  __syncthreads();
  // V8: map(8,4) = (g11,g7); sigma2 remainder folded into read
  #pragma unroll
  for (int s=0;s<4;s++) a[s] = lds[0][swz(s2perm(mapj<8,4>(t,s)))];
  gate4<0>(a, TBL(49)); gate4<1>(a, TBL(50));                   // L3d0 g11,g7
  #pragma unroll
  for (int s=0;s<4;s++) lds[1][swz(mapj<8,4>(t,s))] = a[s];
  __syncthreads();
  // V9: map(1,10) = (g3,g15)
  #pragma unroll
  for (int s=0;s<4;s++) a[s] = lds[1][swz(mapj<1,10>(t,s))];
  gate4<0>(a, TBL(51));                                         // L3d0 g3 -> L3d0 done
  diag4<48,4, (1u<<3),(1u<<15)>(a, tbl, Ic(mapj<1,10>(t,0), o)); // D3_0
  gate4<0>(a, TBL(55)); gate4<1>(a, TBL(52));                   // L3d1 g3,g15
  #pragma unroll
  for (int s=0;s<4;s++) lds[0][swz(mapj<1,10>(t,s))] = a[s];
  __syncthreads();
  // V10: map(4,8) = (g7,g11)
  #pragma unroll
  for (int s=0;s<4;s++) a[s] = lds[0][swz(mapj<4,8>(t,s))];
  gate4<0>(a, TBL(54)); gate4<1>(a, TBL(53));                   // L3d1 g7,g11 -> done
  diag4<52,4, (1u<<7),(1u<<11)>(a, tbl, Ic(mapj<4,8>(t,0), o)); // D3_1
  #pragma unroll
  for (int s=0;s<4;s++) lds[1][swz(mapj<4,8>(t,s))] = a[s];
  __syncthreads();
  // V11: map(4,10) = (g7,g15); sigma3 folded into read
  #pragma unroll
  for (int s=0;s<4;s++) a[s] = lds[1][swz(s3perm(mapj<4,10>(t,s)))];
  gate4<0>(a, TBL(57)); gate4<1>(a, TBL(56));                   // L4d0 g7,g15
  diag4<56,2, (1u<<7),(1u<<15)>(a, tbl, Ic(mapj<4,10>(t,0), o)); // D4_0
  gate4<1>(a, TBL(58));                                         // L4d1 g15
  // sigma4, D4_1, L4d1(g7) dropped: invariant for the g15 marginal.
  float s = 0.f;
  #pragma unroll
  for (int r=0;r<4;r++){
    float w = a[r].x*a[r].x + a[r].y*a[r].y;
    s += (r & 2) ? -w : w;
  }
  #pragma unroll
  for (int off=32; off>0; off>>=1) s += __shfl_down(s, off);
  if ((t & 63) == 0) red[t>>6] = s;
  __syncthreads();
  if (t == 0){
    float tot = 0.f;
    #pragma unroll
    for (int w=0; w<8; w++) tot += red[w];
    atomicAdd(out + batch, tot);
  }
}

extern "C" void kernel_launch(void* const* d_in, const int* in_sizes, int n_in,
                              void* d_out, int out_size, void* d_ws, size_t ws_size,
                              hipStream_t stream) {
  const float* xre = (const float*)d_in[0];
  const float* xim = (const float*)d_in[1];
  const float* p0  = (const float*)d_in[2];
  const float* p1  = (const float*)d_in[3];
  const float* p2  = (const float*)d_in[4];
  const float* p3  = (const float*)d_in[5];
  float* out = (float*)d_out;
  float2* st = (float2*)d_ws;                           // 8 MB state
  float* tbl = (float*)((char*)d_ws + (8u<<20));        // 600-float gate table

  k_setup<<<1, 64, 0, stream>>>(p0, p1, p2, p3, tbl, out);
  k_p1<<<512, 512, 0, stream>>>(xre, xim, tbl, st);
  k_p2<<<512, 512, 0, stream>>>(tbl, st);
  k_p3<<<512, 512, 0, stream>>>(tbl, st);
  k_p4<<<512, 512, 0, stream>>>(tbl, st, out);
}